// Round 1
// 399.681 us; speedup vs baseline: 1.0883x; 1.0883x over previous
//
#include <hip/hip_runtime.h>
#include <hip/hip_bf16.h>

#define BATCH 16
#define SEQ   2048
#define DIM   64
#define CTX_ELEMS (BATCH * SEQ * DIM)
// 0.125 * log2(e)
#define C_EXP2 0.18033688011112042f

typedef __attribute__((ext_vector_type(8))) __bf16 bf16x8;
typedef __attribute__((ext_vector_type(4))) __bf16 bf16x4;
typedef __attribute__((ext_vector_type(4))) float f32x4;

// ---------------- conversion: K fp32 -> bf16 (same layout) ----------------
__global__ void convert_k(const float* __restrict__ K, __bf16* __restrict__ Kb) {
    int i = blockIdx.x * 256 + threadIdx.x;          // one float4 per thread
    const float4* K4 = (const float4*)K;
    float4 v = K4[i];
    bf16x4 o;
    o[0] = (__bf16)v.x; o[1] = (__bf16)v.y; o[2] = (__bf16)v.z; o[3] = (__bf16)v.w;
    ((bf16x4*)Kb)[i] = o;
}

// ---------------- conversion: V fp32 [B][S][D] -> bf16 Vt [B][D][S] ----------------
__global__ void trans_v(const float* __restrict__ V, __bf16* __restrict__ Vt) {
    __shared__ float tile[64][65];
    int b  = blockIdx.x >> 5;
    int kb = (blockIdx.x & 31) * 64;
    int t  = threadIdx.x;
    const float4* V4 = (const float4*)(V + ((size_t)(b * SEQ + kb)) * DIM);
    int d4 = (t & 15) * 4;
#pragma unroll
    for (int r = 0; r < 4; ++r) {
        int k = (t >> 4) + r * 16;
        float4 v = V4[k * (DIM / 4) + (t & 15)];
        tile[k][d4 + 0] = v.x; tile[k][d4 + 1] = v.y;
        tile[k][d4 + 2] = v.z; tile[k][d4 + 3] = v.w;
    }
    __syncthreads();
    int d  = t >> 2;
    int kl = (t & 3) * 16;
    bf16x8 v0, v1;
#pragma unroll
    for (int j = 0; j < 8; ++j) {
        v0[j] = (__bf16)tile[kl + j][d];
        v1[j] = (__bf16)tile[kl + 8 + j][d];
    }
    bf16x8* outv = (bf16x8*)(Vt + ((size_t)(b * DIM + d)) * SEQ + kb + kl);
    outv[0] = v0;
    outv[1] = v1;
}

// ---------------- main fused attention (single-pass, P in registers) ----------------
// grid (128, 16): x = q-tile of 16 rows, y = batch. 8 waves/block, each wave
// owns a 256-wide K chunk. Score MFMA is transposed (A=K, B=Q) so each lane
// holds 4 consecutive k of one q-row. exp2 scores are held in f32 registers
// (p[16] = 64 VGPR) across the softmax reduction -> QK^T + exp2 computed ONCE.
__global__ __launch_bounds__(512, 4)
void attn_main(const float* __restrict__ Q, const __bf16* __restrict__ Kb,
               const __bf16* __restrict__ Vt, float* __restrict__ out) {
    __shared__ __bf16 plds[8][16][40];    // per-wave P tile [q][k-within-32], padded
    __shared__ float  redl[8][16];        // per-wave softmax denom partials
    __shared__ float  ctxred[8][16][65];  // per-wave ctx partials [q][d], padded

    const int tid   = threadIdx.x;
    const int wave  = tid >> 6;
    const int lane  = tid & 63;
    const int quad  = lane >> 4;
    const int l16   = lane & 15;
    const int b     = blockIdx.y;
    const int qbase = blockIdx.x * 16;
    const int kbase = wave * (SEQ / 8);   // 256 keys per wave

    // ---- Q B-fragment: B[n=l16][k=quad*8+j], fp32->bf16 in-register ----
    const float* qrow = Q + ((size_t)(b * SEQ + qbase + l16)) * DIM + quad * 8;
    bf16x8 aQ0, aQ1;
#pragma unroll
    for (int j = 0; j < 8; ++j) {
        aQ0[j] = (__bf16)qrow[j];
        aQ1[j] = (__bf16)qrow[32 + j];
    }

    const bf16x8* Kv = (const bf16x8*)(Kb + (size_t)b * SEQ * DIM);
    const bf16x8* Vv = (const bf16x8*)(Vt + (size_t)b * DIM * SEQ);

    // ---- single pass: scores -> exp2 -> registers, denom on the fly ----
    // p[kt][r] = exp2(score) for q = qbase+l16, k = kbase + kt*16 + quad*4 + r
    f32x4 p[16];
    float lsum = 0.f;
#pragma unroll
    for (int kt = 0; kt < 16; ++kt) {                // fully unrolled: p[] static
        int row = kbase + kt * 16 + l16;             // A m-index = key row
        bf16x8 k0 = Kv[row * 8 + quad];
        bf16x8 k1 = Kv[row * 8 + quad + 4];
        f32x4 acc = {0.f, 0.f, 0.f, 0.f};
        acc = __builtin_amdgcn_mfma_f32_16x16x32_bf16(k0, aQ0, acc, 0, 0, 0);
        acc = __builtin_amdgcn_mfma_f32_16x16x32_bf16(k1, aQ1, acc, 0, 0, 0);
        f32x4 e;
#pragma unroll
        for (int r = 0; r < 4; ++r) {
            e[r] = __builtin_amdgcn_exp2f(acc[r] * C_EXP2);
            lsum += e[r];
        }
        p[kt] = e;
    }
    // reduce across quads (same q = l16 on all quads), then across 8 waves
    lsum += __shfl_xor(lsum, 16, 64);
    lsum += __shfl_xor(lsum, 32, 64);
    if (lane < 16) redl[wave][lane] = lsum;
    __syncthreads();
    float tot = 0.f;
#pragma unroll
    for (int w = 0; w < 8; ++w) tot += redl[w][l16];
    const float rinv = 1.0f / tot;

    // ---- scale + store attn (nontemporal: 268 MB write-once) + PV accumulate ----
    float* attn = out + CTX_ELEMS + (size_t)b * SEQ * SEQ
                + (size_t)(qbase + l16) * SEQ + kbase;
    f32x4 ctx[4];
#pragma unroll
    for (int nt = 0; nt < 4; ++nt) ctx[nt] = (f32x4){0.f, 0.f, 0.f, 0.f};
    const int vbase = kbase / 8;                     // bf16x8 units along k

#pragma unroll
    for (int ch = 0; ch < 8; ++ch) {                 // 8 iters of 32 keys
#pragma unroll
        for (int half = 0; half < 2; ++half) {
            const int kt = ch * 2 + half;
            f32x4 pn = p[kt] * rinv;                 // normalized P, f32
            __builtin_nontemporal_store(pn, (f32x4*)(attn + kt * 16 + quad * 4));
            bf16x4 pb;
            pb[0] = (__bf16)pn[0]; pb[1] = (__bf16)pn[1];
            pb[2] = (__bf16)pn[2]; pb[3] = (__bf16)pn[3];
            *(bf16x4*)&plds[wave][l16][half * 16 + quad * 4] = pb;
        }
        // within-wave LDS round-trip: P D-layout -> A-layout (no barrier needed)
        bf16x8 aP = *(const bf16x8*)&plds[wave][l16][quad * 8];
#pragma unroll
        for (int nt = 0; nt < 4; ++nt) {
            bf16x8 bv = Vv[(nt * 16 + l16) * (SEQ / 8) + vbase + ch * 4 + quad];
            ctx[nt] = __builtin_amdgcn_mfma_f32_16x16x32_bf16(aP, bv, ctx[nt], 0, 0, 0);
        }
    }

    // ---- block-reduce ctx partials across the 8 waves ----
#pragma unroll
    for (int nt = 0; nt < 4; ++nt)
#pragma unroll
        for (int r = 0; r < 4; ++r)
            ctxred[wave][quad * 4 + r][nt * 16 + l16] = ctx[nt][r];
    __syncthreads();
    float* ctxout = out + ((size_t)(b * SEQ + qbase)) * DIM;
    for (int i = tid; i < 16 * DIM; i += 512) {
        int q = i >> 6, d = i & 63;
        float s = 0.f;
#pragma unroll
        for (int w = 0; w < 8; ++w) s += ctxred[w][q][d];
        ctxout[i] = s;
    }
}

// ---------------- fallback (ws too small): one block per query row ----------------
__global__ void attn_slow(const float* __restrict__ Q, const float* __restrict__ K,
                          const float* __restrict__ V, float* __restrict__ out) {
    __shared__ float sc[SEQ];
    __shared__ float qs[DIM];
    __shared__ float red[256];
    int b = blockIdx.y, q = blockIdx.x, t = threadIdx.x;
    const float* qp = Q + ((size_t)(b * SEQ + q)) * DIM;
    if (t < DIM) qs[t] = qp[t];
    __syncthreads();
    for (int k = t; k < SEQ; k += 256) {
        const float* kp = K + ((size_t)(b * SEQ + k)) * DIM;
        float s = 0.f;
        for (int d = 0; d < DIM; ++d) s += qs[d] * kp[d];
        sc[k] = __builtin_amdgcn_exp2f(s * C_EXP2);
    }
    __syncthreads();
    float part = 0.f;
    for (int k = t; k < SEQ; k += 256) part += sc[k];
#pragma unroll
    for (int m = 1; m < 64; m <<= 1) part += __shfl_xor(part, m, 64);
    if ((t & 63) == 0) red[t >> 6] = part;
    __syncthreads();
    float rinv = 1.0f / (red[0] + red[1] + red[2] + red[3]);
    float* attn = out + CTX_ELEMS + ((size_t)b * SEQ + q) * SEQ;
    for (int k = t; k < SEQ; k += 256) attn[k] = sc[k] * rinv;
    int d = t & 63, seg = t >> 6;
    float acc = 0.f;
    for (int k = seg * (SEQ / 4); k < (seg + 1) * (SEQ / 4); ++k)
        acc += sc[k] * V[((size_t)(b * SEQ + k)) * DIM + d];
    __syncthreads();
    red[t] = acc * rinv;
    __syncthreads();
    if (t < 64)
        out[((size_t)(b * SEQ + q)) * DIM + t] = red[t] + red[t + 64] + red[t + 128] + red[t + 192];
}

extern "C" void kernel_launch(void* const* d_in, const int* in_sizes, int n_in,
                              void* d_out, int out_size, void* d_ws, size_t ws_size,
                              hipStream_t stream) {
    const float* Q = (const float*)d_in[0];
    const float* K = (const float*)d_in[1];
    const float* V = (const float*)d_in[2];
    float* out = (float*)d_out;

    size_t need = (size_t)2 * BATCH * SEQ * DIM * sizeof(__bf16);  // Kb + Vt = 8 MB
    if (ws_size >= need) {
        __bf16* Kb = (__bf16*)d_ws;
        __bf16* Vt = Kb + (size_t)BATCH * SEQ * DIM;
        convert_k<<<(BATCH * SEQ * DIM) / (256 * 4), 256, 0, stream>>>(K, Kb);
        trans_v<<<BATCH * (SEQ / 64), 256, 0, stream>>>(V, Vt);
        attn_main<<<dim3(SEQ / 16, BATCH), 512, 0, stream>>>(Q, Kb, Vt, out);
    } else {
        attn_slow<<<dim3(SEQ, BATCH), 256, 0, stream>>>(Q, K, V, out);
    }
}